// Round 3
// baseline (782.781 us; speedup 1.0000x reference)
//
#include <hip/hip_runtime.h>
#include <hip/hip_bf16.h>
#include <math.h>

// Problem constants
#define DDIM   300
#define PFN    12
#define LFN    8
#define ICH    21      // PF + LF + 1
#define TPB    256     // 64 samples/block, 4 threads(lanes)/sample
#define SPB    64      // samples per block
#define SLOT_DW 99     // per-sample feature slot: 9 positions * 11 dwords (22 bf16, 21 used)
#define W1N    3780    // 20*21*9 conv1 weights

__device__ __forceinline__ float lrelu(float v) { return v > 0.0f ? v : 0.2f * v; }

__device__ __forceinline__ unsigned int pack2(float a, float b) {
    union { __hip_bfloat162 h; unsigned int u; } cv;
    cv.h.x = __float2bfloat16(a);
    cv.h.y = __float2bfloat16(b);
    return cv.u;
}
__device__ __forceinline__ float bflo(unsigned int u) {
    union { unsigned int i; float f; } c; c.i = u << 16; return c.f;
}
__device__ __forceinline__ float bfhi(unsigned int u) {
    union { unsigned int i; float f; } c; c.i = u & 0xffff0000u; return c.f;
}

// 3x3 conv (pad=1) on a 3x3 grid: accumulate one input channel into 9 outputs.
// All indices compile-time (fully unrolled) -> o stays in VGPRs.
__device__ __forceinline__ void conv_acc(float o[9], const float* __restrict__ w, const float fv[9]) {
#pragma unroll
    for (int t = 0; t < 9; ++t) {
        const int ky = t / 3 - 1, kx = t % 3 - 1;
        const float wv = w[t];
#pragma unroll
        for (int y = 0; y < 3; ++y) {
            const int iy = y + ky;
            if (iy < 0 || iy > 2) continue;
#pragma unroll
            for (int x = 0; x < 3; ++x) {
                const int ix = x + kx;
                if (ix < 0 || ix > 2) continue;
                o[y * 3 + x] = fmaf(wv, fv[iy * 3 + ix], o[y * 3 + x]);
            }
        }
    }
}

// waves_per_eu pinned at (4,4): LDS (40.4 KB) caps us at 4 blocks/CU = 4 waves/EU
// anyway, so let the RA have the full 512/4 = 128 VGPR budget instead of
// chasing 8 waves/EU (=64 VGPRs) and spilling the conv1 accumulators to scratch.
__attribute__((amdgpu_waves_per_eu(4, 4)))
__launch_bounds__(TPB)
__global__ void disc_kernel(
    const int* __restrict__ state, const int* __restrict__ des,
    const int* __restrict__ act,
    const int* __restrict__ asp_g,   // action_state_pad (S,9)
    const int* __restrict__ pmp_g,   // policy_mask_pad  (S,9)
    const float* __restrict__ path_feature,  // (S,D,12)
    const float* __restrict__ link_feature,  // (S,8)
    const float* __restrict__ w1, const float* __restrict__ b1,   // conv1 (20,21,3,3)
    const float* __restrict__ w2, const float* __restrict__ b2,   // conv2 (30,20,2,2)
    const float* __restrict__ fw1, const float* __restrict__ fb1, // (120,38)
    const float* __restrict__ fw2, const float* __restrict__ fb2, // (84,120)
    const float* __restrict__ fw3, const float* __restrict__ fb3, // (1,84)
    float* __restrict__ out, int n)
{
    __shared__ float w1s[W1N];                    // 15120 B
    __shared__ unsigned int feat[SPB * SLOT_DW];  // 25344 B  -> total 40464 B = 4 blocks/CU

    const int tid = threadIdx.x;

    // Stage conv1 weights to LDS once per block (coalesced).
    for (int i = tid; i < W1N; i += TPB) w1s[i] = w1[i];
    __syncthreads();

    const int lane4  = tid & 3;       // lane within sample quad
    const int lsamp  = tid >> 2;      // sample within block
    const int sample = blockIdx.x * SPB + lsamp;
    if (sample >= n) return;

    const int s  = state[sample];
    const int d  = des[sample];
    const int ai = act[sample];

    const int* asp = asp_g + s * 9;
    const int* pmp = pmp_g + s * 9;
    unsigned int* fslot = feat + lsamp * SLOT_DW;

    // ---- Cooperative gather: lane k handles positions k, k+4, k+8.
    // NEW_INDEX packed as nibbles: p -> {7,0,1,6,8,2,5,4,3}
#pragma unroll
    for (int t = 0; t < 3; ++t) {
        const int p = lane4 + 4 * t;
        if (p < 9) {
            const int a  = (int)((0x345286107ULL >> (4 * p)) & 0xF);
            const int na = asp[a];
            const float m = (float)pmp[a];
            const float4* pf = (const float4*)(path_feature + (na * DDIM + d) * PFN);
            const float4 v0 = pf[0], v1 = pf[1], v2 = pf[2];
            const float4* lf = (const float4*)(link_feature + na * LFN);
            const float4 u0 = lf[0], u1 = lf[1];
            unsigned int* dst = fslot + p * 11;   // 22 bf16 per position (dword aligned)
            dst[0] = pack2(v0.x, v0.y); dst[1] = pack2(v0.z, v0.w);
            dst[2] = pack2(v1.x, v1.y); dst[3] = pack2(v1.z, v1.w);
            dst[4] = pack2(v2.x, v2.y); dst[5] = pack2(v2.z, v2.w);
            dst[6] = pack2(u0.x, u0.y); dst[7] = pack2(u0.z, u0.w);
            dst[8] = pack2(u1.x, u1.y); dst[9] = pack2(u1.z, u1.w);
            dst[10] = pack2(m, 0.0f);             // channel 20 = mask, high half = pad
        }
    }
    // Same-wave cross-lane LDS RAW: drain our wave's ds_writes before reads.
    asm volatile("s_waitcnt lgkmcnt(0)" ::: "memory");

    // ---- conv1: lane k computes output channels [5k, 5k+5)
    const int oc0 = lane4 * 5;
    float o[5][9];
#pragma unroll
    for (int c = 0; c < 5; ++c) {
        const float bb = b1[oc0 + c];
#pragma unroll
        for (int q = 0; q < 9; ++q) o[c][q] = bb;
    }

#pragma unroll 1
    for (int icp = 0; icp < 10; ++icp) {          // ic pairs 0..19
        unsigned int fw[9];
#pragma unroll
        for (int q = 0; q < 9; ++q) fw[q] = fslot[q * 11 + icp];
        float flo[9], fhi[9];
#pragma unroll
        for (int q = 0; q < 9; ++q) { flo[q] = bflo(fw[q]); fhi[q] = bfhi(fw[q]); }
#pragma unroll
        for (int c = 0; c < 5; ++c) {
            const float* wl = w1s + ((oc0 + c) * ICH + 2 * icp) * 9;
            conv_acc(o[c], wl,     flo);
            conv_acc(o[c], wl + 9, fhi);
        }
    }
    {   // ic = 20 (mask channel)
        float f20[9];
#pragma unroll
        for (int q = 0; q < 9; ++q) f20[q] = bflo(fslot[q * 11 + 10]);
#pragma unroll
        for (int c = 0; c < 5; ++c)
            conv_acc(o[c], w1s + ((oc0 + c) * ICH + 20) * 9, f20);
    }

    // ---- lrelu + 2x2 maxpool (stride 1) on local 5 channels
    float pooled[5][4];
#pragma unroll
    for (int c = 0; c < 5; ++c) {
        float v[9];
#pragma unroll
        for (int q = 0; q < 9; ++q) v[q] = lrelu(o[c][q]);
        pooled[c][0] = fmaxf(fmaxf(v[0], v[1]), fmaxf(v[3], v[4]));
        pooled[c][1] = fmaxf(fmaxf(v[1], v[2]), fmaxf(v[4], v[5]));
        pooled[c][2] = fmaxf(fmaxf(v[3], v[4]), fmaxf(v[6], v[7]));
        pooled[c][3] = fmaxf(fmaxf(v[4], v[5]), fmaxf(v[7], v[8]));
    }

    // ---- conv2 (2x2 VALID): per-lane partial over its 5 oc, quad butterfly reduce.
    // FULLY unrolled: x30[j] must be statically indexed or it goes to scratch (rule #20).
    float x30[30];
#pragma unroll
    for (int j = 0; j < 30; ++j) {
        const float4* wr = (const float4*)(w2 + j * 80 + oc0 * 4);  // 16B aligned
        float acc = 0.0f;
#pragma unroll
        for (int c = 0; c < 5; ++c) {
            const float4 wv = wr[c];
            acc = fmaf(wv.x, pooled[c][0], acc);
            acc = fmaf(wv.y, pooled[c][1], acc);
            acc = fmaf(wv.z, pooled[c][2], acc);
            acc = fmaf(wv.w, pooled[c][3], acc);
        }
        acc += __shfl_xor(acc, 1, 64);
        acc += __shfl_xor(acc, 2, 64);
        x30[j] = lrelu(acc + b2[j]);
    }

    // ---- fc1 (38->120): lane k computes rows [30k, 30k+30)
    // FULLY unrolled: h1[jj] writes must be statically indexed (rule #20).
    float h1[30];
    const int j0 = lane4 * 30;
#pragma unroll
    for (int jj = 0; jj < 30; ++jj) {
        const float* wr = fw1 + (j0 + jj) * 38;
        float acc = fb1[j0 + jj] + wr[30 + ai];   // one-hot(act) contribution
        const float2* wp = (const float2*)wr;     // 8B aligned (38*4 = 152)
#pragma unroll
        for (int m = 0; m < 15; ++m) {
            const float2 wv = wp[m];
            acc = fmaf(wv.x, x30[2 * m],     acc);
            acc = fmaf(wv.y, x30[2 * m + 1], acc);
        }
        h1[jj] = lrelu(acc);
    }

    // ---- fc2 (120->84) + fc3 (84->1): per-lane partial dot over its 30 h1,
    // butterfly reduce per output, fold straight into fc3 (no h2 array).
    // Partial unroll OK: h1 reads use static inner index, only scalar z written.
    float z = fb3[0];
#pragma unroll 4
    for (int i = 0; i < 84; ++i) {
        const float2* wp = (const float2*)(fw2 + i * 120 + j0);  // 8B aligned
        float a = 0.0f;
#pragma unroll
        for (int m = 0; m < 15; ++m) {
            const float2 wv = wp[m];
            a = fmaf(wv.x, h1[2 * m],     a);
            a = fmaf(wv.y, h1[2 * m + 1], a);
        }
        a += __shfl_xor(a, 1, 64);
        a += __shfl_xor(a, 2, 64);
        z = fmaf(fw3[i], lrelu(a + fb2[i]), z);
    }

    if (lane4 == 0)
        out[sample] = 1.0f / (1.0f + __expf(-z));
}

extern "C" void kernel_launch(void* const* d_in, const int* in_sizes, int n_in,
                              void* d_out, int out_size, void* d_ws, size_t ws_size,
                              hipStream_t stream) {
    const int*   state = (const int*)d_in[0];
    const int*   des   = (const int*)d_in[1];
    const int*   act   = (const int*)d_in[2];
    const int*   asp   = (const int*)d_in[3];
    const int*   pmp   = (const int*)d_in[4];
    const float* pathf = (const float*)d_in[5];
    const float* linkf = (const float*)d_in[6];
    const float* w1    = (const float*)d_in[7];
    const float* b1    = (const float*)d_in[8];
    const float* w2    = (const float*)d_in[9];
    const float* b2    = (const float*)d_in[10];
    const float* fw1   = (const float*)d_in[11];
    const float* fb1   = (const float*)d_in[12];
    const float* fw2   = (const float*)d_in[13];
    const float* fb2   = (const float*)d_in[14];
    const float* fw3   = (const float*)d_in[15];
    const float* fb3   = (const float*)d_in[16];

    const int n = in_sizes[0];
    dim3 grid((n + SPB - 1) / SPB), block(TPB);
    hipLaunchKernelGGL(disc_kernel, grid, block, 0, stream,
                       state, des, act, asp, pmp, pathf, linkf,
                       w1, b1, w2, b2, fw1, fb1, fw2, fb2, fw3, fb3,
                       (float*)d_out, n);
}

// Round 4
// 690.877 us; speedup vs baseline: 1.1330x; 1.1330x over previous
//
#include <hip/hip_runtime.h>
#include <hip/hip_bf16.h>
#include <math.h>

// Problem constants
#define DDIM   300
#define PFN    12
#define LFN    8
#define ICH    21      // PF + LF + 1
#define TPB    64      // ONE wave per block; 4 lanes per sample
#define SPB    16      // samples per block
#define SLOT_DW 99     // per-sample feature slot: 9 positions * 11 dwords

__device__ __forceinline__ float lrelu(float v) { return v > 0.0f ? v : 0.2f * v; }

__device__ __forceinline__ unsigned int pack2(float a, float b) {
    union { __hip_bfloat162 h; unsigned int u; } cv;
    cv.h.x = __float2bfloat16(a);
    cv.h.y = __float2bfloat16(b);
    return cv.u;
}
__device__ __forceinline__ float bflo(unsigned int u) {
    union { unsigned int i; float f; } c; c.i = u << 16; return c.f;
}
__device__ __forceinline__ float bfhi(unsigned int u) {
    union { unsigned int i; float f; } c; c.i = u & 0xffff0000u; return c.f;
}

// 3x3 conv (pad=1) on a 3x3 grid: accumulate one input channel into 9 outputs.
__device__ __forceinline__ void conv_acc(float o[9], const float* __restrict__ w, const float fv[9]) {
#pragma unroll
    for (int t = 0; t < 9; ++t) {
        const int ky = t / 3 - 1, kx = t % 3 - 1;
        const float wv = w[t];
#pragma unroll
        for (int y = 0; y < 3; ++y) {
            const int iy = y + ky;
            if (iy < 0 || iy > 2) continue;
#pragma unroll
            for (int x = 0; x < 3; ++x) {
                const int ix = x + kx;
                if (ix < 0 || ix > 2) continue;
                o[y * 3 + x] = fmaf(wv, fv[iy * 3 + ix], o[y * 3 + x]);
            }
        }
    }
}

// (64,1): the ONLY empirically-verified config that gives the RA a liberal
// VGPR budget on this toolchain (round 0: 132 VGPRs, no spill storm).
// 256-thread blocks with any waves-per-eu annotation pinned us to 64 VGPRs
// and ~1.1 GB/dispatch of scratch-eviction HBM traffic.
__launch_bounds__(TPB, 1)
__global__ void disc_kernel(
    const int* __restrict__ state, const int* __restrict__ des,
    const int* __restrict__ act,
    const int* __restrict__ asp_g,   // action_state_pad (S,9)
    const int* __restrict__ pmp_g,   // policy_mask_pad  (S,9)
    const float* __restrict__ path_feature,  // (S,D,12)
    const float* __restrict__ link_feature,  // (S,8)
    const float* __restrict__ w1, const float* __restrict__ b1,   // conv1 (20,21,3,3)
    const float* __restrict__ w2, const float* __restrict__ b2,   // conv2 (30,20,2,2)
    const float* __restrict__ fw1, const float* __restrict__ fb1, // (120,38)
    const float* __restrict__ fw2, const float* __restrict__ fb2, // (84,120)
    const float* __restrict__ fw3, const float* __restrict__ fb3, // (1,84)
    float* __restrict__ out, int n)
{
    __shared__ unsigned int feat[SPB * SLOT_DW];  // 6336 B

    const int tid    = threadIdx.x;
    const int lane4  = tid & 3;       // lane within sample quad
    const int lsamp  = tid >> 2;      // sample within block
    const int sample = blockIdx.x * SPB + lsamp;
    if (sample >= n) return;

    const int s  = state[sample];
    const int d  = des[sample];
    const int ai = act[sample];

    const int* asp = asp_g + s * 9;
    const int* pmp = pmp_g + s * 9;
    unsigned int* fslot = feat + lsamp * SLOT_DW;

    // ---- Cooperative gather: lane k handles positions k, k+4, k+8.
    // NEW_INDEX packed as nibbles: p -> {7,0,1,6,8,2,5,4,3}
#pragma unroll
    for (int t = 0; t < 3; ++t) {
        const int p = lane4 + 4 * t;
        if (p < 9) {
            const int a  = (int)((0x345286107ULL >> (4 * p)) & 0xF);
            const int na = asp[a];
            const float m = (float)pmp[a];
            const float4* pf = (const float4*)(path_feature + (na * DDIM + d) * PFN);
            const float4 v0 = pf[0], v1 = pf[1], v2 = pf[2];
            const float4* lf = (const float4*)(link_feature + na * LFN);
            const float4 u0 = lf[0], u1 = lf[1];
            unsigned int* dst = fslot + p * 11;   // 22 bf16 per position (dword aligned)
            dst[0] = pack2(v0.x, v0.y); dst[1] = pack2(v0.z, v0.w);
            dst[2] = pack2(v1.x, v1.y); dst[3] = pack2(v1.z, v1.w);
            dst[4] = pack2(v2.x, v2.y); dst[5] = pack2(v2.z, v2.w);
            dst[6] = pack2(u0.x, u0.y); dst[7] = pack2(u0.z, u0.w);
            dst[8] = pack2(u1.x, u1.y); dst[9] = pack2(u1.z, u1.w);
            dst[10] = pack2(m, 0.0f);             // channel 20 = mask, high half = pad
        }
    }
    // One wave per block: quad lanes share the wave, so ordering our own
    // ds_writes before cross-lane ds_reads only needs lgkmcnt drain.
    asm volatile("s_waitcnt lgkmcnt(0)" ::: "memory");

    // ---- conv1: lane k computes output channels [5k, 5k+5)
    // Weights from global: w1 is 15 KB -> L1-resident, no LDS staging needed.
    const int oc0 = lane4 * 5;
    float o[5][9];
#pragma unroll
    for (int c = 0; c < 5; ++c) {
        const float bb = b1[oc0 + c];
#pragma unroll
        for (int q = 0; q < 9; ++q) o[c][q] = bb;
    }

#pragma unroll 1
    for (int icp = 0; icp < 10; ++icp) {          // ic pairs 0..19
        unsigned int fw[9];
#pragma unroll
        for (int q = 0; q < 9; ++q) fw[q] = fslot[q * 11 + icp];
        float flo[9], fhi[9];
#pragma unroll
        for (int q = 0; q < 9; ++q) { flo[q] = bflo(fw[q]); fhi[q] = bfhi(fw[q]); }
#pragma unroll
        for (int c = 0; c < 5; ++c) {
            const float* wl = w1 + ((oc0 + c) * ICH + 2 * icp) * 9;
            conv_acc(o[c], wl,     flo);
            conv_acc(o[c], wl + 9, fhi);
        }
    }
    {   // ic = 20 (mask channel)
        float f20[9];
#pragma unroll
        for (int q = 0; q < 9; ++q) f20[q] = bflo(fslot[q * 11 + 10]);
#pragma unroll
        for (int c = 0; c < 5; ++c)
            conv_acc(o[c], w1 + ((oc0 + c) * ICH + 20) * 9, f20);
    }

    // ---- lrelu + 2x2 maxpool (stride 1) on local 5 channels
    float pooled[5][4];
#pragma unroll
    for (int c = 0; c < 5; ++c) {
        float v[9];
#pragma unroll
        for (int q = 0; q < 9; ++q) v[q] = lrelu(o[c][q]);
        pooled[c][0] = fmaxf(fmaxf(v[0], v[1]), fmaxf(v[3], v[4]));
        pooled[c][1] = fmaxf(fmaxf(v[1], v[2]), fmaxf(v[4], v[5]));
        pooled[c][2] = fmaxf(fmaxf(v[3], v[4]), fmaxf(v[6], v[7]));
        pooled[c][3] = fmaxf(fmaxf(v[4], v[5]), fmaxf(v[7], v[8]));
    }

    // ---- conv2 (2x2 VALID): per-lane partial over its 5 oc, quad butterfly reduce.
    float x30[30];
#pragma unroll
    for (int j = 0; j < 30; ++j) {
        const float4* wr = (const float4*)(w2 + j * 80 + oc0 * 4);  // 16B aligned
        float acc = 0.0f;
#pragma unroll
        for (int c = 0; c < 5; ++c) {
            const float4 wv = wr[c];
            acc = fmaf(wv.x, pooled[c][0], acc);
            acc = fmaf(wv.y, pooled[c][1], acc);
            acc = fmaf(wv.z, pooled[c][2], acc);
            acc = fmaf(wv.w, pooled[c][3], acc);
        }
        acc += __shfl_xor(acc, 1, 64);
        acc += __shfl_xor(acc, 2, 64);
        x30[j] = lrelu(acc + b2[j]);
    }

    // ---- fc1 (38->120): lane k computes rows [30k, 30k+30)
    float h1[30];
    const int j0 = lane4 * 30;
#pragma unroll
    for (int jj = 0; jj < 30; ++jj) {
        const float* wr = fw1 + (j0 + jj) * 38;
        float acc = fb1[j0 + jj] + wr[30 + ai];   // one-hot(act) contribution
        const float2* wp = (const float2*)wr;     // 8B aligned (38*4 = 152)
#pragma unroll
        for (int m = 0; m < 15; ++m) {
            const float2 wv = wp[m];
            acc = fmaf(wv.x, x30[2 * m],     acc);
            acc = fmaf(wv.y, x30[2 * m + 1], acc);
        }
        h1[jj] = lrelu(acc);
    }

    // ---- fc2 (120->84) + fc3 (84->1): per-lane partial dot over its 30 h1,
    // butterfly reduce per output, fold straight into fc3 (no h2 array).
    float z = fb3[0];
#pragma unroll 4
    for (int i = 0; i < 84; ++i) {
        const float2* wp = (const float2*)(fw2 + i * 120 + j0);  // 8B aligned
        float a = 0.0f;
#pragma unroll
        for (int m = 0; m < 15; ++m) {
            const float2 wv = wp[m];
            a = fmaf(wv.x, h1[2 * m],     a);
            a = fmaf(wv.y, h1[2 * m + 1], a);
        }
        a += __shfl_xor(a, 1, 64);
        a += __shfl_xor(a, 2, 64);
        z = fmaf(fw3[i], lrelu(a + fb2[i]), z);
    }

    if (lane4 == 0)
        out[sample] = 1.0f / (1.0f + __expf(-z));
}

extern "C" void kernel_launch(void* const* d_in, const int* in_sizes, int n_in,
                              void* d_out, int out_size, void* d_ws, size_t ws_size,
                              hipStream_t stream) {
    const int*   state = (const int*)d_in[0];
    const int*   des   = (const int*)d_in[1];
    const int*   act   = (const int*)d_in[2];
    const int*   asp   = (const int*)d_in[3];
    const int*   pmp   = (const int*)d_in[4];
    const float* pathf = (const float*)d_in[5];
    const float* linkf = (const float*)d_in[6];
    const float* w1    = (const float*)d_in[7];
    const float* b1    = (const float*)d_in[8];
    const float* w2    = (const float*)d_in[9];
    const float* b2    = (const float*)d_in[10];
    const float* fw1   = (const float*)d_in[11];
    const float* fb1   = (const float*)d_in[12];
    const float* fw2   = (const float*)d_in[13];
    const float* fb2   = (const float*)d_in[14];
    const float* fw3   = (const float*)d_in[15];
    const float* fb3   = (const float*)d_in[16];

    const int n = in_sizes[0];
    dim3 grid((n + SPB - 1) / SPB), block(TPB);
    hipLaunchKernelGGL(disc_kernel, grid, block, 0, stream,
                       state, des, act, asp, pmp, pathf, linkf,
                       w1, b1, w2, b2, fw1, fb1, fw2, fb2, fw3, fb3,
                       (float*)d_out, n);
}